// Round 7
// baseline (69.261 us; speedup 1.0000x reference)
//
#include <hip/hip_runtime.h>
#include <stdint.h>
#include <math.h>

// Problem constants (match reference)
#define B_N   32768
#define INDIM 256
#define HID   256
#define NE    8
#define KM1   4
#define KCLS  5
#define BM    64
#define CAP   8192                 // fixed per-expert segment capacity (~4096 expected, 60-sigma headroom)
#define TPE   (CAP / BM)           // 128 tiles per expert
#define NBLK  (NE * TPE)           // 1024 blocks

typedef __bf16 bf16x8 __attribute__((ext_vector_type(8)));
typedef float  f32x4  __attribute__((ext_vector_type(4)));
typedef unsigned short u16x8 __attribute__((ext_vector_type(8)));

__device__ __forceinline__ unsigned short f2bf(float f) {
    union { float f; unsigned u; } v; v.f = f;
    unsigned r = v.u + 0x7FFFu + ((v.u >> 16) & 1u);   // RNE
    return (unsigned short)(r >> 16);
}
__device__ __forceinline__ float bf2f(unsigned short b) {
    union { unsigned u; float f; } v; v.u = ((unsigned)b) << 16;
    return v.f;
}
// chunk-of-8-bf16 swizzle (bank-verified): slot = chunk ^ (row&7)
__device__ __forceinline__ int SWZ(int r, int c) { return c ^ (r & 7); }

__device__ __forceinline__ void gload_lds16(const void* g, void* l) {
    __builtin_amdgcn_global_load_lds(
        (__attribute__((address_space(1))) unsigned int*)(g),
        (__attribute__((address_space(3))) unsigned int*)(l),
        16, 0, 0);
}

// ==== k_prep: W1 pack + self-scan sort + x convert/scatter into tile images ====
// 256 blocks x 256 threads. Block b owns samples [b*128, b*128+128).
__global__ __launch_bounds__(256) void k_prep(
    const float* __restrict__ W1, const float* __restrict__ x,
    const int* __restrict__ sidx,
    unsigned short* __restrict__ w1p, unsigned short* __restrict__ xb,
    int* __restrict__ perm, int* __restrict__ meta)
{
    __shared__ float tile[64][65];
    __shared__ int wsum[4][NE];     // scan partial counts per wave
    __shared__ int gcnt[2][NE];     // own-128 per-64-group counts
    __shared__ int pcs[NE];         // exclusive prefix counts (samples < b*128)
    __shared__ int posbuf[128];

    int t    = threadIdx.x;
    int b    = blockIdx.x;
    int lane = t & 63;
    int wave = t >> 6;

    // (a) pack-role W1 tile load (blocks 0..127); latency hides under the scan
    if (b < 128) {
        int e  = b >> 4, ti = (b >> 2) & 3, th = b & 3;
        const float* src = W1 + (((size_t)e * INDIM) + (size_t)ti * 64) * HID + th * 64;
        int col = t & 63, r0 = (t >> 6) * 16;
        #pragma unroll
        for (int rr = 0; rr < 16; ++rr)
            tile[r0 + rr][col] = src[(size_t)(r0 + rr) * HID + col];
    }

    // (b) exclusive scan: count experts in sidx[0 .. b*128), ballot-based
    int cnt[NE] = {0, 0, 0, 0, 0, 0, 0, 0};   // static-indexed via unroll
    int nch = (b * 128) >> 6;                  // number of 64-sample chunks
    for (int j = wave; j < nch; j += 4) {
        int v = sidx[j * 64 + lane];
        #pragma unroll
        for (int t2 = 0; t2 < NE; ++t2) {
            unsigned long long m = __ballot(v == t2);
            cnt[t2] += (int)__popcll(m);
        }
    }
    if (lane == 0) {
        #pragma unroll
        for (int t2 = 0; t2 < NE; ++t2) wsum[wave][t2] = cnt[t2];
    }
    __syncthreads();
    if (t < NE) pcs[t] = wsum[0][t] + wsum[1][t] + wsum[2][t] + wsum[3][t];

    // (c) rank own 128 samples (waves 0,1 fully active -> ballots safe)
    int e_own = 0, posw = 0;
    if (t < 128) {
        e_own = sidx[b * 128 + t];
        #pragma unroll
        for (int t2 = 0; t2 < NE; ++t2) {
            unsigned long long m = __ballot(e_own == t2);
            if (e_own == t2) posw = (int)__popcll(m & ((1ull << lane) - 1ull));
            if (lane == t2) gcnt[wave][t2] = (int)__popcll(m);
        }
    }
    __syncthreads();   // pcs + gcnt ready
    if (t < 128) {
        int grp  = (wave == 1) ? gcnt[0][e_own] : 0;
        int rank = pcs[e_own] + grp + posw;
        int pos  = e_own * CAP + rank;
        posbuf[t] = pos;
        perm[pos] = b * 128 + t;
    }
    if (b == 255 && t < NE) meta[t] = pcs[t] + gcnt[0][t] + gcnt[1][t];

    // (d) pack-role write w1p (fragment order: B[lane] = W1[k][n], n=lane&15, kc=lane>>4)
    if (b < 128) {
        int e  = b >> 4, ti = (b >> 2) & 3, th = b & 3;
        int u = t >> 6;
        #pragma unroll
        for (int ks2 = 0; ks2 < 2; ++ks2) {
            int ks = ti * 2 + ks2, nb = th * 4 + u;
            u16x8 v;
            #pragma unroll
            for (int j = 0; j < 8; ++j)
                v[j] = f2bf(tile[ks2 * 32 + (lane >> 4) * 8 + j][u * 16 + (lane & 15)]);
            *(u16x8*)&w1p[((((size_t)e * 8 + ks) * 16 + nb) * 64 + lane) * 8] = v;
        }
    }
    __syncthreads();   // posbuf ready

    // (e) convert+scatter x rows into xb tile images (pre-swizzled, bf16).
    // Threads t and t+128 write halves of sample (t&127)'s row.
    {
        int si  = t & 127, h = t >> 7;
        int i   = b * 128 + si;
        int pos = posbuf[si];
        int r   = pos & (BM - 1);
        const float* xr = x + (size_t)i * INDIM + h * 128;
        unsigned short* dst = xb + (size_t)pos * 256;
        #pragma unroll
        for (int cc = 0; cc < 16; ++cc) {
            int ch   = h * 16 + cc;
            int slot = SWZ(r, ch);
            f32x4 a0 = *(const f32x4*)(xr + cc * 8);
            f32x4 a1 = *(const f32x4*)(xr + cc * 8 + 4);
            u16x8 v;
            v[0] = f2bf(a0[0]); v[1] = f2bf(a0[1]); v[2] = f2bf(a0[2]); v[3] = f2bf(a0[3]);
            v[4] = f2bf(a1[0]); v[5] = f2bf(a1[1]); v[6] = f2bf(a1[2]); v[7] = f2bf(a1[3]);
            *(u16x8*)&dst[slot * 8] = v;
        }
    }
}

// ==== k_main: grouped GEMM from pre-staged xb; B from XCD-local L2 ====
__global__ __launch_bounds__(256, 4) void k_main(
    const float* __restrict__ b1, const float* __restrict__ W2,
    const float* __restrict__ b2,
    const unsigned short* __restrict__ w1p,
    const unsigned short* __restrict__ xb,
    const int* __restrict__ perm, const int* __restrict__ meta,
    float* __restrict__ out)
{
    __shared__ unsigned short xs[BM * 256];   // 32KB tile image (SWZ), reused for h
    __shared__ float w2s[1040];               // W2[e] bank-padded

    // XCD swizzle: blockIdx&7 = XCD = expert -> w1p[e] (128KB) stays L2-resident
    int bid = (blockIdx.x & 7) * TPE + (blockIdx.x >> 3);
    int e   = bid >> 7;
    int tl  = bid & (TPE - 1);
    int cnt = meta[e];
    int rb  = tl * BM;
    if (rb >= cnt) return;                    // dead tile
    int segc = cnt - rb;                      // live rows in this tile (may be >BM)

    int tid  = threadIdx.x;
    int lane = tid & 63;
    int wave = tid >> 6;
    int r15  = lane & 15;
    int hi   = lane >> 4;

    // stage xs: 8 x global_load_lds dwordx4, linear dest, pre-swizzled source
    const unsigned short* xbt = xb + ((size_t)e * CAP + rb) * 256;
    #pragma unroll
    for (int it = 0; it < 8; ++it)
        gload_lds16(xbt + ((size_t)it * 256 + tid) * 8, &xs[it * 2048 + wave * 512]);

    // B fragment prefetch (L2)
    const unsigned short* w1pe = w1p + (size_t)e * (8 * 16 * 64 * 8);
    auto loadB = [&](int ks, int ni) -> bf16x8 {
        return *(const bf16x8*)&w1pe[(((ks * 16 + wave * 4 + ni) * 64) + lane) * 8];
    };
    bf16x8 bcur[4];
    #pragma unroll
    for (int ni = 0; ni < 4; ++ni) bcur[ni] = loadB(0, ni);

    {   // stage W2[e] (4KB) -> LDS padded
        const float* w2e = W2 + (size_t)e * HID * KM1;
        f32x4 wv = *(const f32x4*)(w2e + (size_t)tid * 4);
        *(f32x4*)&w2s[tid * 4 + (tid >> 6) * 4] = wv;
    }
    __syncthreads();   // xs (vmcnt drained) + w2s ready

    f32x4 acc[4][4];
    #pragma unroll
    for (int mi = 0; mi < 4; ++mi)
        #pragma unroll
        for (int ni = 0; ni < 4; ++ni) {
            f32x4 z = {0.f, 0.f, 0.f, 0.f};
            acc[mi][ni] = z;
        }

    #pragma unroll
    for (int ks = 0; ks < 8; ++ks) {
        bf16x8 bnext[4];
        if (ks < 7) {
            #pragma unroll
            for (int ni = 0; ni < 4; ++ni) bnext[ni] = loadB(ks + 1, ni);
        }
        bf16x8 af[4];
        #pragma unroll
        for (int mi = 0; mi < 4; ++mi) {
            int r = mi * 16 + r15;
            af[mi] = *(const bf16x8*)&xs[r * 256 + (SWZ(r, ks * 4 + hi) << 3)];
        }
        #pragma unroll
        for (int mi = 0; mi < 4; ++mi)
            #pragma unroll
            for (int ni = 0; ni < 4; ++ni)
                acc[mi][ni] = __builtin_amdgcn_mfma_f32_16x16x32_bf16(
                    af[mi], bcur[ni], acc[mi][ni], 0, 0, 0);
        if (ks < 7) {
            #pragma unroll
            for (int ni = 0; ni < 4; ++ni) bcur[ni] = bnext[ni];
        }
    }
    __syncthreads();   // all xs reads done before h overwrite

    // h = relu(acc + b1) -> xs (bf16, SWZ). D layout: col=lane&15, row=(lane>>4)*4+j
    float b1v[4];
    #pragma unroll
    for (int ni = 0; ni < 4; ++ni)
        b1v[ni] = b1[e * HID + wave * 64 + ni * 16 + r15];
    #pragma unroll
    for (int mi = 0; mi < 4; ++mi) {
        #pragma unroll
        for (int ni = 0; ni < 4; ++ni) {
            int colg  = wave * 64 + ni * 16 + r15;
            int chunk = colg >> 3;
            #pragma unroll
            for (int j = 0; j < 4; ++j) {
                int rowg = mi * 16 + hi * 4 + j;
                float h = fmaxf(acc[mi][ni][j] + b1v[ni], 0.f);
                xs[rowg * 256 + (SWZ(rowg, chunk) << 3) + (colg & 7)] = f2bf(h);
            }
        }
    }
    __syncthreads();

    // layer 2: 4-way split-K per row (bank-uniform: group = s ^ (row&7))
    int row = tid >> 2;
    int q   = tid & 3;
    f32x4 lac = {0.f, 0.f, 0.f, 0.f};
    #pragma unroll
    for (int s = 0; s < 8; ++s) {
        int c = q * 8 + s;
        u16x8 hv = *(const u16x8*)&xs[row * 256 + (SWZ(row, c) << 3)];
        #pragma unroll
        for (int j = 0; j < 8; ++j) {
            int k = c * 8 + j;
            float hf = bf2f(hv[j]);
            const f32x4 wv = *(const f32x4*)&w2s[k * 4 + (k >> 6) * 4];
            lac[0] += hf * wv[0]; lac[1] += hf * wv[1];
            lac[2] += hf * wv[2]; lac[3] += hf * wv[3];
        }
    }
    #pragma unroll
    for (int c4 = 0; c4 < 4; ++c4) {
        lac[c4] += __shfl_xor(lac[c4], 1, 4);
        lac[c4] += __shfl_xor(lac[c4], 2, 4);
    }

    if (row < segc) {
        int smp = perm[(size_t)e * CAP + rb + row];
        const float* b2e = b2 + e * KM1;
        float l0 = lac[0] + b2e[0], l1 = lac[1] + b2e[1];
        float l2 = lac[2] + b2e[2], l3 = lac[3] + b2e[3];
        float q0 = 1.f / (1.f + expf(-l0)), q1 = 1.f / (1.f + expf(-l1));
        float q2v = 1.f / (1.f + expf(-l2)), q3 = 1.f / (1.f + expf(-l3));
        float p0 = fmaxf(1.f - q0, 1e-8f), p1 = fmaxf(q0 - q1, 1e-8f);
        float p2 = fmaxf(q1 - q2v, 1e-8f), p3 = fmaxf(q2v - q3, 1e-8f);
        float p4 = fmaxf(q3, 1e-8f);
        float inv = 1.f / (p0 + p1 + p2 + p3 + p4);
        float myl = (q & 1) ? ((q & 2) ? l3 : l1) : ((q & 2) ? l2 : l0);
        float myp = (q & 1) ? ((q & 2) ? p3 : p1) : ((q & 2) ? p2 : p0);
        out[(size_t)smp * KM1 + q] = myl;
        float* probs = out + (size_t)B_N * KM1;
        probs[(size_t)smp * KCLS + q] = myp * inv;
        if (q == 3) probs[(size_t)smp * KCLS + 4] = p4 * inv;
    }
}

extern "C" void kernel_launch(void* const* d_in, const int* in_sizes, int n_in,
                              void* d_out, int out_size, void* d_ws, size_t ws_size,
                              hipStream_t stream) {
    const float* x   = (const float*)d_in[0];
    const int*   sid = (const int*)d_in[1];
    const float* W1  = (const float*)d_in[2];
    const float* b1  = (const float*)d_in[3];
    const float* W2  = (const float*)d_in[4];
    const float* b2  = (const float*)d_in[5];
    float* out = (float*)d_out;

    char* ws = (char*)d_ws;
    unsigned short* w1p = (unsigned short*)ws;                   // 1 MB
    unsigned short* xb  = (unsigned short*)(ws + 1048576);       // 8*8192*512 B = 32 MB
    int* perm = (int*)(ws + 1048576 + 33554432);                 // 64K*4 = 256 KB
    int* meta = (int*)(ws + 1048576 + 33554432 + 262144);        // 32 B

    k_prep<<<dim3(256),  dim3(256), 0, stream>>>(W1, x, sid, w1p, xb, perm, meta);
    k_main<<<dim3(NBLK), dim3(256), 0, stream>>>(b1, W2, b2, w1p, xb, perm, meta, out);
}

// Round 8
// 42.193 us; speedup vs baseline: 1.6415x; 1.6415x over previous
//
#include <hip/hip_runtime.h>
#include <stdint.h>
#include <math.h>

// Problem constants (match reference)
#define B_N   32768
#define INDIM 256
#define HID   256
#define NE    8
#define KM1   4
#define KCLS  5
#define BM    64
#define CAP   8192                 // fixed per-expert segment capacity (~4096 expected)
#define TPE   (CAP / BM)           // 128 tiles per expert
#define NBLK  (NE * TPE)           // 1024 blocks

typedef __bf16 bf16x8 __attribute__((ext_vector_type(8)));
typedef float  f32x4  __attribute__((ext_vector_type(4)));
typedef unsigned short u16x8 __attribute__((ext_vector_type(8)));

__device__ __forceinline__ unsigned short f2bf(float f) {
    union { float f; unsigned u; } v; v.f = f;
    unsigned r = v.u + 0x7FFFu + ((v.u >> 16) & 1u);   // RNE
    return (unsigned short)(r >> 16);
}
__device__ __forceinline__ float bf2f(unsigned short b) {
    union { unsigned u; float f; } v; v.u = ((unsigned)b) << 16;
    return v.f;
}
// chunk-of-8-bf16 swizzle (bank-verified): slot = chunk ^ (row&7)
__device__ __forceinline__ int SWZ(int r, int c) { return c ^ (r & 7); }

__device__ __forceinline__ void gload_lds16(const void* g, void* l) {
    __builtin_amdgcn_global_load_lds(
        (__attribute__((address_space(1))) unsigned int*)(g),
        (__attribute__((address_space(3))) unsigned int*)(l),
        16, 0, 0);
}

// ==== prep 1: W1 pack + per-128-sample histogram partials (plain stores) ====
// 128 blocks x 256 threads. Block b: W1 sub-tile pack + histogram of samples
// [b*256, b*256+256) split into two 128-sample partials.
__global__ __launch_bounds__(256) void k_w1t(const float* __restrict__ W1,
                                             const int* __restrict__ sidx,
                                             unsigned short* __restrict__ w1p,
                                             int* __restrict__ part) {
    __shared__ float tile[64][65];
    __shared__ int wc[4][NE];
    int t    = threadIdx.x;
    int b    = blockIdx.x;
    int lane = t & 63;
    int wave = t >> 6;

    // histogram via ballot (4 fully-active waves)
    int es = sidx[b * 256 + t];
    #pragma unroll
    for (int t2 = 0; t2 < NE; ++t2) {
        unsigned long long m = __ballot(es == t2);
        if (lane == t2) wc[wave][t2] = (int)__popcll(m);
    }

    int e  = b >> 4, ti = (b >> 2) & 3, th = b & 3;
    const float* src = W1 + (((size_t)e * INDIM) + (size_t)ti * 64) * HID + th * 64;
    int col = t & 63, r0 = (t >> 6) * 16;
    #pragma unroll
    for (int rr = 0; rr < 16; ++rr)
        tile[r0 + rr][col] = src[(size_t)(r0 + rr) * HID + col];
    __syncthreads();

    if (t < NE) {
        part[(2 * b) * NE + t]     = wc[0][t] + wc[1][t];
        part[(2 * b + 1) * NE + t] = wc[2][t] + wc[3][t];
    }

    // pack w1p: B-fragment order w1p[e][ks][nb][lane][8]
    int u = t >> 6;
    #pragma unroll
    for (int ks2 = 0; ks2 < 2; ++ks2) {
        int ks = ti * 2 + ks2, nb = th * 4 + u;
        u16x8 v;
        #pragma unroll
        for (int j = 0; j < 8; ++j)
            v[j] = f2bf(tile[ks2 * 32 + (lane >> 4) * 8 + j][u * 16 + (lane & 15)]);
        *(u16x8*)&w1p[((((size_t)e * 8 + ks) * 16 + nb) * 64 + lane) * 8] = v;
    }
}

// ==== prep 2: parallel prefix + rank + x convert/scatter into tile images ====
// 256 blocks x 256 threads. Block b owns samples [b*128, b*128+128).
__global__ __launch_bounds__(256) void k_xscat(
    const float* __restrict__ x, const int* __restrict__ sidx,
    const int* __restrict__ part,
    unsigned short* __restrict__ xb, int* __restrict__ perm,
    int* __restrict__ meta)
{
    __shared__ int pp[256][NE];     // all 128-sample partials (8 KB)
    __shared__ int pr[8][NE][2];    // [range][expert][{below,all}]
    __shared__ int pre8[NE], tot8[NE];
    __shared__ int wc0[NE];
    __shared__ int posbuf[128];

    int t    = threadIdx.x;
    int b    = blockIdx.x;
    int lane = t & 63;
    int wave = t >> 6;

    // load partials (coalesced: thread t -> chunk t's 8 counts)
    #pragma unroll
    for (int e2 = 0; e2 < NE; ++e2) pp[t][e2] = part[t * NE + e2];

    // rank own 128 samples (waves 0,1 fully active)
    int e_own = 0, posw = 0;
    if (t < 128) {
        e_own = sidx[b * 128 + t];
        #pragma unroll
        for (int t2 = 0; t2 < NE; ++t2) {
            unsigned long long m = __ballot(e_own == t2);
            if (e_own == t2) posw = (int)__popcll(m & ((1ull << lane) - 1ull));
            if (wave == 0 && lane == t2) wc0[t2] = (int)__popcll(m);
        }
    }
    __syncthreads();

    // parallel prefix: 64 threads, range r covers chunks [r*32, r*32+32)
    if (t < 64) {
        int e2 = t & 7, r = t >> 3;
        int sb = 0, sa = 0;
        #pragma unroll
        for (int c = 0; c < 32; ++c) {
            int ch = r * 32 + c;
            int v  = pp[ch][e2];
            sb += (ch < b) ? v : 0;
            sa += v;
        }
        pr[r][e2][0] = sb; pr[r][e2][1] = sa;
    }
    __syncthreads();
    if (t < NE) {
        int sb = 0, sa = 0;
        #pragma unroll
        for (int r = 0; r < 8; ++r) { sb += pr[r][t][0]; sa += pr[r][t][1]; }
        pre8[t] = sb; tot8[t] = sa;
        meta[t] = sa;                      // same value from every block: benign
    }
    __syncthreads();

    if (t < 128) {
        int rank = pre8[e_own] + ((wave == 1) ? wc0[e_own] : 0) + posw;
        int pos  = e_own * CAP + rank;
        posbuf[t] = pos;
        perm[pos] = b * 128 + t;
    }
    __syncthreads();

    // convert + scatter x rows into xb tile images (pre-swizzled bf16).
    // Threads t and t+128 write the two halves of sample (t&127)'s row.
    {
        int si  = t & 127, h = t >> 7;
        int pos = posbuf[si];
        int r   = pos & (BM - 1);
        const float* xr = x + (size_t)(b * 128 + si) * INDIM + h * 128;
        unsigned short* dst = xb + (size_t)pos * 256;
        #pragma unroll
        for (int cc = 0; cc < 16; ++cc) {
            int ch   = h * 16 + cc;
            int slot = SWZ(r, ch);
            f32x4 a0 = *(const f32x4*)(xr + cc * 8);
            f32x4 a1 = *(const f32x4*)(xr + cc * 8 + 4);
            u16x8 v;
            v[0] = f2bf(a0[0]); v[1] = f2bf(a0[1]); v[2] = f2bf(a0[2]); v[3] = f2bf(a0[3]);
            v[4] = f2bf(a1[0]); v[5] = f2bf(a1[1]); v[6] = f2bf(a1[2]); v[7] = f2bf(a1[3]);
            *(u16x8*)&dst[slot * 8] = v;
        }
    }
}

// ==== k_main: grouped GEMM from pre-staged xb; B from XCD-local L2 ====
__global__ __launch_bounds__(256, 4) void k_main(
    const float* __restrict__ b1, const float* __restrict__ W2,
    const float* __restrict__ b2,
    const unsigned short* __restrict__ w1p,
    const unsigned short* __restrict__ xb,
    const int* __restrict__ perm, const int* __restrict__ meta,
    float* __restrict__ out)
{
    __shared__ unsigned short xs[BM * 256];   // 32KB tile image (SWZ), reused for h
    __shared__ float w2s[1040];               // W2[e] bank-padded

    // XCD swizzle: blockIdx&7 = XCD = expert -> w1p[e] (128KB) stays L2-resident
    int bid = (blockIdx.x & 7) * TPE + (blockIdx.x >> 3);
    int e   = bid >> 7;
    int tl  = bid & (TPE - 1);
    int cnt = meta[e];
    int rb  = tl * BM;
    if (rb >= cnt) return;                    // dead tile
    int segc = cnt - rb;

    int tid  = threadIdx.x;
    int lane = tid & 63;
    int wave = tid >> 6;
    int r15  = lane & 15;
    int hi   = lane >> 4;

    // stage xs: 8 x global_load_lds dwordx4, linear dest, pre-swizzled source
    const unsigned short* xbt = xb + ((size_t)e * CAP + rb) * 256;
    #pragma unroll
    for (int it = 0; it < 8; ++it)
        gload_lds16(xbt + ((size_t)it * 256 + tid) * 8, &xs[it * 2048 + wave * 512]);

    // B fragment prefetch (L2)
    const unsigned short* w1pe = w1p + (size_t)e * (8 * 16 * 64 * 8);
    auto loadB = [&](int ks, int ni) -> bf16x8 {
        return *(const bf16x8*)&w1pe[(((ks * 16 + wave * 4 + ni) * 64) + lane) * 8];
    };
    bf16x8 bcur[4];
    #pragma unroll
    for (int ni = 0; ni < 4; ++ni) bcur[ni] = loadB(0, ni);

    {   // stage W2[e] (4KB) -> LDS padded
        const float* w2e = W2 + (size_t)e * HID * KM1;
        f32x4 wv = *(const f32x4*)(w2e + (size_t)tid * 4);
        *(f32x4*)&w2s[tid * 4 + (tid >> 6) * 4] = wv;
    }
    __syncthreads();   // xs (vmcnt drained) + w2s ready

    f32x4 acc[4][4];
    #pragma unroll
    for (int mi = 0; mi < 4; ++mi)
        #pragma unroll
        for (int ni = 0; ni < 4; ++ni) {
            f32x4 z = {0.f, 0.f, 0.f, 0.f};
            acc[mi][ni] = z;
        }

    #pragma unroll
    for (int ks = 0; ks < 8; ++ks) {
        bf16x8 bnext[4];
        if (ks < 7) {
            #pragma unroll
            for (int ni = 0; ni < 4; ++ni) bnext[ni] = loadB(ks + 1, ni);
        }
        bf16x8 af[4];
        #pragma unroll
        for (int mi = 0; mi < 4; ++mi) {
            int r = mi * 16 + r15;
            af[mi] = *(const bf16x8*)&xs[r * 256 + (SWZ(r, ks * 4 + hi) << 3)];
        }
        #pragma unroll
        for (int mi = 0; mi < 4; ++mi)
            #pragma unroll
            for (int ni = 0; ni < 4; ++ni)
                acc[mi][ni] = __builtin_amdgcn_mfma_f32_16x16x32_bf16(
                    af[mi], bcur[ni], acc[mi][ni], 0, 0, 0);
        if (ks < 7) {
            #pragma unroll
            for (int ni = 0; ni < 4; ++ni) bcur[ni] = bnext[ni];
        }
    }
    __syncthreads();   // all xs reads done before h overwrite

    // h = relu(acc + b1) -> xs (bf16, SWZ). D layout: col=lane&15, row=(lane>>4)*4+j
    float b1v[4];
    #pragma unroll
    for (int ni = 0; ni < 4; ++ni)
        b1v[ni] = b1[e * HID + wave * 64 + ni * 16 + r15];
    #pragma unroll
    for (int mi = 0; mi < 4; ++mi) {
        #pragma unroll
        for (int ni = 0; ni < 4; ++ni) {
            int colg  = wave * 64 + ni * 16 + r15;
            int chunk = colg >> 3;
            #pragma unroll
            for (int j = 0; j < 4; ++j) {
                int rowg = mi * 16 + hi * 4 + j;
                float h = fmaxf(acc[mi][ni][j] + b1v[ni], 0.f);
                xs[rowg * 256 + (SWZ(rowg, chunk) << 3) + (colg & 7)] = f2bf(h);
            }
        }
    }
    __syncthreads();

    // layer 2: 4-way split-K per row (bank-spread via SWZ rotation)
    int row = tid >> 2;
    int q   = tid & 3;
    f32x4 lac = {0.f, 0.f, 0.f, 0.f};
    #pragma unroll
    for (int s = 0; s < 8; ++s) {
        int c = q * 8 + s;
        u16x8 hv = *(const u16x8*)&xs[row * 256 + (SWZ(row, c) << 3)];
        #pragma unroll
        for (int j = 0; j < 8; ++j) {
            int k = c * 8 + j;
            float hf = bf2f(hv[j]);
            const f32x4 wv = *(const f32x4*)&w2s[k * 4 + (k >> 6) * 4];
            lac[0] += hf * wv[0]; lac[1] += hf * wv[1];
            lac[2] += hf * wv[2]; lac[3] += hf * wv[3];
        }
    }
    #pragma unroll
    for (int c4 = 0; c4 < 4; ++c4) {
        lac[c4] += __shfl_xor(lac[c4], 1, 4);
        lac[c4] += __shfl_xor(lac[c4], 2, 4);
    }

    if (row < segc) {
        int smp = perm[(size_t)e * CAP + rb + row];
        const float* b2e = b2 + e * KM1;
        float l0 = lac[0] + b2e[0], l1 = lac[1] + b2e[1];
        float l2 = lac[2] + b2e[2], l3 = lac[3] + b2e[3];
        float q0 = 1.f / (1.f + expf(-l0)), q1 = 1.f / (1.f + expf(-l1));
        float q2v = 1.f / (1.f + expf(-l2)), q3 = 1.f / (1.f + expf(-l3));
        float p0 = fmaxf(1.f - q0, 1e-8f), p1 = fmaxf(q0 - q1, 1e-8f);
        float p2 = fmaxf(q1 - q2v, 1e-8f), p3 = fmaxf(q2v - q3, 1e-8f);
        float p4 = fmaxf(q3, 1e-8f);
        float inv = 1.f / (p0 + p1 + p2 + p3 + p4);
        float myl = (q & 1) ? ((q & 2) ? l3 : l1) : ((q & 2) ? l2 : l0);
        float myp = (q & 1) ? ((q & 2) ? p3 : p1) : ((q & 2) ? p2 : p0);
        out[(size_t)smp * KM1 + q] = myl;
        float* probs = out + (size_t)B_N * KM1;
        probs[(size_t)smp * KCLS + q] = myp * inv;
        if (q == 3) probs[(size_t)smp * KCLS + 4] = p4 * inv;
    }
}

extern "C" void kernel_launch(void* const* d_in, const int* in_sizes, int n_in,
                              void* d_out, int out_size, void* d_ws, size_t ws_size,
                              hipStream_t stream) {
    const float* x   = (const float*)d_in[0];
    const int*   sid = (const int*)d_in[1];
    const float* W1  = (const float*)d_in[2];
    const float* b1  = (const float*)d_in[3];
    const float* W2  = (const float*)d_in[4];
    const float* b2  = (const float*)d_in[5];
    float* out = (float*)d_out;

    char* ws = (char*)d_ws;
    unsigned short* w1p = (unsigned short*)ws;                   // 1 MB
    unsigned short* xb  = (unsigned short*)(ws + 1048576);       // 32 MB
    int* perm = (int*)(ws + 1048576 + 33554432);                 // 256 KB
    int* part = (int*)(ws + 1048576 + 33554432 + 262144);        // 8 KB
    int* meta = (int*)(ws + 1048576 + 33554432 + 262144 + 8192); // 32 B

    k_w1t  <<<dim3(128),  dim3(256), 0, stream>>>(W1, sid, w1p, part);
    k_xscat<<<dim3(256),  dim3(256), 0, stream>>>(x, sid, part, xb, perm, meta);
    k_main <<<dim3(NBLK), dim3(256), 0, stream>>>(b1, W2, b2, w1p, xb, perm, meta, out);
}

// Round 9
// 39.032 us; speedup vs baseline: 1.7745x; 1.0810x over previous
//
#include <hip/hip_runtime.h>
#include <stdint.h>
#include <math.h>

// Problem constants (match reference)
#define B_N   32768
#define INDIM 256
#define HID   256
#define NE    8
#define KM1   4
#define KCLS  5
#define BM    64
#define CAP   8192                 // fixed per-expert segment capacity (~4096 expected)
#define TPE   (CAP / BM)           // 128 tiles per expert
#define NBLK  (NE * TPE)           // 1024 blocks

typedef __bf16 bf16x8 __attribute__((ext_vector_type(8)));
typedef float  f32x4  __attribute__((ext_vector_type(4)));
typedef unsigned short u16x8 __attribute__((ext_vector_type(8)));

__device__ __forceinline__ unsigned short f2bf(float f) {
    union { float f; unsigned u; } v; v.f = f;
    unsigned r = v.u + 0x7FFFu + ((v.u >> 16) & 1u);   // RNE
    return (unsigned short)(r >> 16);
}
__device__ __forceinline__ float bf2f(unsigned short b) {
    union { unsigned u; float f; } v; v.u = ((unsigned)b) << 16;
    return v.f;
}
// chunk-of-8-bf16 swizzle (bank-verified): slot = chunk ^ (row&7)
__device__ __forceinline__ int SWZ(int r, int c) { return c ^ (r & 7); }

__device__ __forceinline__ void gload_lds16(const void* g, void* l) {
    __builtin_amdgcn_global_load_lds(
        (__attribute__((address_space(1))) unsigned int*)(g),
        (__attribute__((address_space(3))) unsigned int*)(l),
        16, 0, 0);
}

// ==== prep 1: W1 pack + per-128-sample histogram partials (plain stores) ====
__global__ __launch_bounds__(256) void k_w1t(const float* __restrict__ W1,
                                             const int* __restrict__ sidx,
                                             unsigned short* __restrict__ w1p,
                                             int* __restrict__ part) {
    __shared__ float tile[64][65];
    __shared__ int wc[4][NE];
    int t    = threadIdx.x;
    int b    = blockIdx.x;
    int lane = t & 63;
    int wave = t >> 6;

    // histogram via ballot (4 fully-active waves)
    int es = sidx[b * 256 + t];
    #pragma unroll
    for (int t2 = 0; t2 < NE; ++t2) {
        unsigned long long m = __ballot(es == t2);
        if (lane == t2) wc[wave][t2] = (int)__popcll(m);
    }

    int e  = b >> 4, ti = (b >> 2) & 3, th = b & 3;
    const float* src = W1 + (((size_t)e * INDIM) + (size_t)ti * 64) * HID + th * 64;
    int col = t & 63, r0 = (t >> 6) * 16;
    #pragma unroll
    for (int rr = 0; rr < 16; ++rr)
        tile[r0 + rr][col] = src[(size_t)(r0 + rr) * HID + col];
    __syncthreads();

    if (t < NE) {
        part[(2 * b) * NE + t]     = wc[0][t] + wc[1][t];
        part[(2 * b + 1) * NE + t] = wc[2][t] + wc[3][t];
    }

    // pack w1p: B-fragment order w1p[e][ks][nb][lane][8]
    int u = t >> 6;
    #pragma unroll
    for (int ks2 = 0; ks2 < 2; ++ks2) {
        int ks = ti * 2 + ks2, nb = th * 4 + u;
        u16x8 v;
        #pragma unroll
        for (int j = 0; j < 8; ++j)
            v[j] = f2bf(tile[ks2 * 32 + (lane >> 4) * 8 + j][u * 16 + (lane & 15)]);
        *(u16x8*)&w1p[((((size_t)e * 8 + ks) * 16 + nb) * 64 + lane) * 8] = v;
    }
}

// ==== prep 2: prefix + rank only. Writes pos[i] for every sample. ====
// 256 blocks x 256 threads; block b ranks samples [b*128, b*128+128).
__global__ __launch_bounds__(256) void k_rank(
    const int* __restrict__ sidx, const int* __restrict__ part,
    int* __restrict__ pos, int* __restrict__ perm, int* __restrict__ meta)
{
    __shared__ int pp[NE][260];     // transposed partials (pad kills write conflicts)
    __shared__ int pr[8][NE][2];    // [range][expert][{below,all}]
    __shared__ int pre8[NE], tot8[NE], wc0[NE];

    int t    = threadIdx.x;
    int b    = blockIdx.x;
    int lane = t & 63;
    int wave = t >> 6;

    // load partials: part[chunk][e] -> pp[e][chunk] (coalesced 32B per thread)
    #pragma unroll
    for (int e2 = 0; e2 < NE; ++e2) pp[e2][t] = part[t * NE + e2];

    // rank own 128 samples (waves 0,1 fully active)
    int e_own = 0, posw = 0;
    if (t < 128) {
        e_own = sidx[b * 128 + t];
        #pragma unroll
        for (int t2 = 0; t2 < NE; ++t2) {
            unsigned long long m = __ballot(e_own == t2);
            if (e_own == t2) posw = (int)__popcll(m & ((1ull << lane) - 1ull));
            if (wave == 0 && lane == t2) wc0[t2] = (int)__popcll(m);
        }
    }
    __syncthreads();

    // parallel prefix: 64 threads, range r covers chunks [r*32, r*32+32)
    if (t < 64) {
        int e2 = t & 7, r = t >> 3;
        int sb = 0, sa = 0;
        #pragma unroll
        for (int c = 0; c < 32; ++c) {
            int ch = r * 32 + c;
            int v  = pp[e2][ch];
            sb += (ch < b) ? v : 0;
            sa += v;
        }
        pr[r][e2][0] = sb; pr[r][e2][1] = sa;
    }
    __syncthreads();
    if (t < NE) {
        int sb = 0, sa = 0;
        #pragma unroll
        for (int r = 0; r < 8; ++r) { sb += pr[r][t][0]; sa += pr[r][t][1]; }
        pre8[t] = sb; tot8[t] = sa;
        meta[t] = sa;                      // same value from every block: benign
    }
    __syncthreads();

    if (t < 128) {
        int rank = pre8[e_own] + ((wave == 1) ? wc0[e_own] : 0) + posw;
        int p    = e_own * CAP + rank;
        pos[b * 128 + t] = p;
        perm[p] = b * 128 + t;
    }
}

// ==== prep 3: pure streaming convert+scatter x -> xb (pre-swizzled bf16) ====
// 2048 blocks x 256 threads (8 blocks/CU). 16 threads per row, 2 chunks each.
__global__ __launch_bounds__(256) void k_xconv(
    const float* __restrict__ x, const int* __restrict__ pos,
    unsigned short* __restrict__ xb)
{
    int g    = blockIdx.x;             // 16 rows per block
    int rloc = threadIdx.x >> 4;
    int p    = threadIdx.x & 15;
    int smp  = g * 16 + rloc;
    int ps   = pos[smp];
    int r    = ps & (BM - 1);
    const float* xr = x + (size_t)smp * INDIM + p * 16;
    unsigned short* dst = xb + (size_t)ps * 256;
    #pragma unroll
    for (int cc = 0; cc < 2; ++cc) {
        int ch = p * 2 + cc;
        f32x4 a0 = *(const f32x4*)(xr + cc * 8);
        f32x4 a1 = *(const f32x4*)(xr + cc * 8 + 4);
        u16x8 v;
        v[0] = f2bf(a0[0]); v[1] = f2bf(a0[1]); v[2] = f2bf(a0[2]); v[3] = f2bf(a0[3]);
        v[4] = f2bf(a1[0]); v[5] = f2bf(a1[1]); v[6] = f2bf(a1[2]); v[7] = f2bf(a1[3]);
        *(u16x8*)&dst[SWZ(r, ch) * 8] = v;
    }
}

// ==== k_main: grouped GEMM from pre-staged xb; B from XCD-local L2 ====
__global__ __launch_bounds__(256, 4) void k_main(
    const float* __restrict__ b1, const float* __restrict__ W2,
    const float* __restrict__ b2,
    const unsigned short* __restrict__ w1p,
    const unsigned short* __restrict__ xb,
    const int* __restrict__ perm, const int* __restrict__ meta,
    float* __restrict__ out)
{
    __shared__ unsigned short xs[BM * 256];   // 32KB tile image (SWZ), reused for h
    __shared__ float w2s[1040];               // W2[e] bank-padded

    // XCD swizzle: blockIdx&7 = XCD = expert -> w1p[e] (128KB) stays L2-resident
    int bid = (blockIdx.x & 7) * TPE + (blockIdx.x >> 3);
    int e   = bid >> 7;
    int tl  = bid & (TPE - 1);
    int cnt = meta[e];
    int rb  = tl * BM;
    if (rb >= cnt) return;                    // dead tile
    int segc = cnt - rb;

    int tid  = threadIdx.x;
    int lane = tid & 63;
    int wave = tid >> 6;
    int r15  = lane & 15;
    int hi   = lane >> 4;

    // stage xs: 8 x global_load_lds dwordx4, linear dest, pre-swizzled source
    const unsigned short* xbt = xb + ((size_t)e * CAP + rb) * 256;
    #pragma unroll
    for (int it = 0; it < 8; ++it)
        gload_lds16(xbt + ((size_t)it * 256 + tid) * 8, &xs[it * 2048 + wave * 512]);

    // B fragment prefetch (L2)
    const unsigned short* w1pe = w1p + (size_t)e * (8 * 16 * 64 * 8);
    auto loadB = [&](int ks, int ni) -> bf16x8 {
        return *(const bf16x8*)&w1pe[(((ks * 16 + wave * 4 + ni) * 64) + lane) * 8];
    };
    bf16x8 bcur[4];
    #pragma unroll
    for (int ni = 0; ni < 4; ++ni) bcur[ni] = loadB(0, ni);

    {   // stage W2[e] (4KB) -> LDS padded
        const float* w2e = W2 + (size_t)e * HID * KM1;
        f32x4 wv = *(const f32x4*)(w2e + (size_t)tid * 4);
        *(f32x4*)&w2s[tid * 4 + (tid >> 6) * 4] = wv;
    }
    __syncthreads();   // xs (vmcnt drained) + w2s ready

    f32x4 acc[4][4];
    #pragma unroll
    for (int mi = 0; mi < 4; ++mi)
        #pragma unroll
        for (int ni = 0; ni < 4; ++ni) {
            f32x4 z = {0.f, 0.f, 0.f, 0.f};
            acc[mi][ni] = z;
        }

    #pragma unroll
    for (int ks = 0; ks < 8; ++ks) {
        bf16x8 bnext[4];
        if (ks < 7) {
            #pragma unroll
            for (int ni = 0; ni < 4; ++ni) bnext[ni] = loadB(ks + 1, ni);
        }
        bf16x8 af[4];
        #pragma unroll
        for (int mi = 0; mi < 4; ++mi) {
            int r = mi * 16 + r15;
            af[mi] = *(const bf16x8*)&xs[r * 256 + (SWZ(r, ks * 4 + hi) << 3)];
        }
        #pragma unroll
        for (int mi = 0; mi < 4; ++mi)
            #pragma unroll
            for (int ni = 0; ni < 4; ++ni)
                acc[mi][ni] = __builtin_amdgcn_mfma_f32_16x16x32_bf16(
                    af[mi], bcur[ni], acc[mi][ni], 0, 0, 0);
        if (ks < 7) {
            #pragma unroll
            for (int ni = 0; ni < 4; ++ni) bcur[ni] = bnext[ni];
        }
    }
    __syncthreads();   // all xs reads done before h overwrite

    // h = relu(acc + b1) -> xs (bf16, SWZ). D layout: col=lane&15, row=(lane>>4)*4+j
    float b1v[4];
    #pragma unroll
    for (int ni = 0; ni < 4; ++ni)
        b1v[ni] = b1[e * HID + wave * 64 + ni * 16 + r15];
    #pragma unroll
    for (int mi = 0; mi < 4; ++mi) {
        #pragma unroll
        for (int ni = 0; ni < 4; ++ni) {
            int colg  = wave * 64 + ni * 16 + r15;
            int chunk = colg >> 3;
            #pragma unroll
            for (int j = 0; j < 4; ++j) {
                int rowg = mi * 16 + hi * 4 + j;
                float h = fmaxf(acc[mi][ni][j] + b1v[ni], 0.f);
                xs[rowg * 256 + (SWZ(rowg, chunk) << 3) + (colg & 7)] = f2bf(h);
            }
        }
    }
    __syncthreads();

    // layer 2: 4-way split-K per row (bank-spread via SWZ rotation)
    int row = tid >> 2;
    int q   = tid & 3;
    f32x4 lac = {0.f, 0.f, 0.f, 0.f};
    #pragma unroll
    for (int s = 0; s < 8; ++s) {
        int c = q * 8 + s;
        u16x8 hv = *(const u16x8*)&xs[row * 256 + (SWZ(row, c) << 3)];
        #pragma unroll
        for (int j = 0; j < 8; ++j) {
            int k = c * 8 + j;
            float hf = bf2f(hv[j]);
            const f32x4 wv = *(const f32x4*)&w2s[k * 4 + (k >> 6) * 4];
            lac[0] += hf * wv[0]; lac[1] += hf * wv[1];
            lac[2] += hf * wv[2]; lac[3] += hf * wv[3];
        }
    }
    #pragma unroll
    for (int c4 = 0; c4 < 4; ++c4) {
        lac[c4] += __shfl_xor(lac[c4], 1, 4);
        lac[c4] += __shfl_xor(lac[c4], 2, 4);
    }

    if (row < segc) {
        int smp = perm[(size_t)e * CAP + rb + row];
        const float* b2e = b2 + e * KM1;
        float l0 = lac[0] + b2e[0], l1 = lac[1] + b2e[1];
        float l2 = lac[2] + b2e[2], l3 = lac[3] + b2e[3];
        float q0 = 1.f / (1.f + expf(-l0)), q1 = 1.f / (1.f + expf(-l1));
        float q2v = 1.f / (1.f + expf(-l2)), q3 = 1.f / (1.f + expf(-l3));
        float p0 = fmaxf(1.f - q0, 1e-8f), p1 = fmaxf(q0 - q1, 1e-8f);
        float p2 = fmaxf(q1 - q2v, 1e-8f), p3 = fmaxf(q2v - q3, 1e-8f);
        float p4 = fmaxf(q3, 1e-8f);
        float inv = 1.f / (p0 + p1 + p2 + p3 + p4);
        float myl = (q & 1) ? ((q & 2) ? l3 : l1) : ((q & 2) ? l2 : l0);
        float myp = (q & 1) ? ((q & 2) ? p3 : p1) : ((q & 2) ? p2 : p0);
        out[(size_t)smp * KM1 + q] = myl;
        float* probs = out + (size_t)B_N * KM1;
        probs[(size_t)smp * KCLS + q] = myp * inv;
        if (q == 3) probs[(size_t)smp * KCLS + 4] = p4 * inv;
    }
}

extern "C" void kernel_launch(void* const* d_in, const int* in_sizes, int n_in,
                              void* d_out, int out_size, void* d_ws, size_t ws_size,
                              hipStream_t stream) {
    const float* x   = (const float*)d_in[0];
    const int*   sid = (const int*)d_in[1];
    const float* W1  = (const float*)d_in[2];
    const float* b1  = (const float*)d_in[3];
    const float* W2  = (const float*)d_in[4];
    const float* b2  = (const float*)d_in[5];
    float* out = (float*)d_out;

    char* ws = (char*)d_ws;
    unsigned short* w1p = (unsigned short*)ws;                       // 1 MB
    unsigned short* xb  = (unsigned short*)(ws + 1048576);           // 32 MB
    int* perm = (int*)(ws + 34603008);                               // 256 KB
    int* part = (int*)(ws + 34865152);                               // 8 KB
    int* meta = (int*)(ws + 34873344);                               // 32 B
    int* pos  = (int*)(ws + 34873600);                               // 128 KB

    k_w1t  <<<dim3(128),  dim3(256), 0, stream>>>(W1, sid, w1p, part);
    k_rank <<<dim3(256),  dim3(256), 0, stream>>>(sid, part, pos, perm, meta);
    k_xconv<<<dim3(2048), dim3(256), 0, stream>>>(x, pos, xb);
    k_main <<<dim3(NBLK), dim3(256), 0, stream>>>(b1, W2, b2, w1p, xb, perm, meta, out);
}